// Round 1
// baseline (284.469 us; speedup 1.0000x reference)
//
#include <hip/hip_runtime.h>

typedef __attribute__((ext_vector_type(4))) float float4v;

// Kernel 1: pib[row,f] = sum_e x[row,e]*W[f,e] + bias[f]
//           pj [row,f] = sum_e x[row,e]*W[f,256+e]
// 4 rows per block (256 blocks): W read once per block -> 128 MB total L2
// traffic instead of 512 MB. Thread f keeps 8 accumulators (4 rows x 2
// halves); W chunks reused across the 4 rows. xs LDS reads are wave-uniform
// (broadcast, conflict-free).
__global__ __launch_bounds__(256) void gemm_pipj(
    const float* __restrict__ x, const float* __restrict__ W,
    const float* __restrict__ bias,
    float* __restrict__ pib, float* __restrict__ pj) {
    const int r0 = blockIdx.x * 4;
    const int f = threadIdx.x;
    __shared__ float xs[4][256];
#pragma unroll
    for (int k = 0; k < 4; ++k)
        xs[k][f] = x[(size_t)(r0 + k) * 256 + f];
    __syncthreads();

    const float4v* wr = (const float4v*)(W + (size_t)f * 512);
    float acc0[4] = {0.f, 0.f, 0.f, 0.f};
    float acc1[4] = {0.f, 0.f, 0.f, 0.f};
#pragma unroll 4
    for (int e4 = 0; e4 < 64; ++e4) {
        float4v w1 = wr[e4];        // cols e4*4..+3       (pi half)
        float4v w2 = wr[e4 + 64];   // cols 256+e4*4..+3   (pj half)
#pragma unroll
        for (int r = 0; r < 4; ++r) {
            float x0 = xs[r][e4 * 4 + 0];
            float x1 = xs[r][e4 * 4 + 1];
            float x2 = xs[r][e4 * 4 + 2];
            float x3 = xs[r][e4 * 4 + 3];
            acc0[r] += x0 * w1.x + x1 * w1.y + x2 * w1.z + x3 * w1.w;
            acc1[r] += x0 * w2.x + x1 * w2.y + x2 * w2.z + x3 * w2.w;
        }
    }
    float bv = bias[f];
#pragma unroll
    for (int r = 0; r < 4; ++r) {
        pib[(size_t)(r0 + r) * 256 + f] = acc0[r] + bv;
        pj [(size_t)(r0 + r) * 256 + f] = acc1[r];
    }
}

// Kernel 2: out[bi, j, f] = pib[bi, f] + pj[b*256+j, f],  bi = b*256+i.
// RESTRUCTURED: blockIdx.x = bi*2 + half. Wave w handles j = half*128 +
// w*32 .. +31 (32 rows per thread, one long load->add->store stream).
// 2048 blocks x 4 waves = 8192 waves = exactly 32 waves/CU: full occupancy
// in ONE dispatch round, pib load amortized 32x (was 4x), and each wave
// issues a 32-deep pipelined store stream instead of 4 stores-then-retire.
// Traffic unchanged (268 MB nt write-once + L2-resident pj reads); this
// attacks store-pipeline depth and per-block launch/drain overhead.
__global__ __launch_bounds__(256) void bcast_add(
    const float* __restrict__ pib, const float* __restrict__ pj,
    float* __restrict__ out) {
    const int bi   = blockIdx.x >> 1;    // b*256 + i
    const int half = blockIdx.x & 1;
    const int t = threadIdx.x;
    const int w = t >> 6;                // wave 0..3
    const int f0 = (t & 63) * 4;
    const int b = bi >> 8;
    const int j0 = half * 128 + w * 32;

    const float4v a = *(const float4v*)(pib + (size_t)bi * 256 + f0);
    const float* pjbase = pj + ((size_t)(b * 256 + j0)) * 256 + f0;
    float* obase = out + (((size_t)bi * 256) + j0) * 256 + f0;
#pragma unroll 8
    for (int jj = 0; jj < 32; ++jj) {
        float4v p = *(const float4v*)(pjbase + (size_t)jj * 256);
        float4v v = a + p;
        __builtin_nontemporal_store(v, (float4v*)(obase + (size_t)jj * 256));
    }
}

extern "C" void kernel_launch(void* const* d_in, const int* in_sizes, int n_in,
                              void* d_out, int out_size, void* d_ws, size_t ws_size,
                              hipStream_t stream) {
    const float* x    = (const float*)d_in[0];  // (4,256,256) fp32
    const float* W    = (const float*)d_in[1];  // (256,512)   fp32
    const float* bias = (const float*)d_in[2];  // (256,)      fp32
    float* out = (float*)d_out;                 // (4,256,256,256) fp32

    float* pib = (float*)d_ws;            // 1024*256 fp32 = 1 MiB
    float* pj  = pib + 1024 * 256;        // 1024*256 fp32 = 1 MiB

    gemm_pipj<<<256, 256, 0, stream>>>(x, W, bias, pib, pj);
    bcast_add<<<2048, 256, 0, stream>>>(pib, pj, out);
}

// Round 2
// 280.225 us; speedup vs baseline: 1.0151x; 1.0151x over previous
//
#include <hip/hip_runtime.h>

typedef __attribute__((ext_vector_type(4))) float float4v;

// Kernel 0: Wt[c][a] = W[a][c].  W is (256, 512) row-major; Wt is (512, 256).
// Classic LDS tile transpose: both global read and write fully coalesced.
// 512 KB once -> ~2 us. This lets the GEMM read W with lanes over f
// (contiguous) instead of 2KB-strided (64 cache lines per instruction).
__global__ __launch_bounds__(256) void transposeW(
    const float* __restrict__ W, float* __restrict__ Wt) {
    __shared__ float tile[64][65];
    const int ta = blockIdx.x & 3;   // row-tile of W (f), 0..3
    const int tc = blockIdx.x >> 2;  // col-tile of W (c), 0..7
    const int lx = threadIdx.x & 63;
    const int ly = threadIdx.x >> 6; // 0..3
#pragma unroll
    for (int rr = 0; rr < 64; rr += 4)
        tile[rr + ly][lx] = W[(size_t)(ta * 64 + rr + ly) * 512 + tc * 64 + lx];
    __syncthreads();
#pragma unroll
    for (int rr = 0; rr < 64; rr += 4)
        Wt[(size_t)(tc * 64 + rr + ly) * 256 + ta * 64 + lx] = tile[lx][rr + ly];
}

// Kernel 1: pib[row,f] = sum_e x[row,e]*W[f,e] + bias[f]
//           pj [row,f] = sum_e x[row,e]*W[f,256+e]
// v2: reads Wt (transposed W) so each wave-load is 64 lanes x 16B
// CONTIGUOUS (1 KB/instr, ~1 cache line per lane-group) instead of the old
// 2KB-strided pattern (64 lines/instr, TA-issue-serialized ~14 us).
// Block = 4 x-rows; wave rw owns row r0+rw; thread owns f0..f0+3 via float4.
// W traffic unchanged (512 KB/block from L2, 128 MB total ~ 4 us floor).
__global__ __launch_bounds__(256) void gemm_pipj(
    const float* __restrict__ x, const float* __restrict__ Wt,
    const float* __restrict__ bias,
    float* __restrict__ pib, float* __restrict__ pj) {
    const int r0 = blockIdx.x * 4;
    const int t = threadIdx.x;
    const int rw = t >> 6;           // row within block (wave id)
    const int fq = t & 63;           // float4 index within f
    __shared__ float xs[4][256];
    // x rows r0..r0+3 are 1024 contiguous floats
#pragma unroll
    for (int k = 0; k < 4; ++k)
        ((float*)xs)[k * 256 + t] = x[(size_t)r0 * 256 + k * 256 + t];
    __syncthreads();

    const float4v* wt = (const float4v*)Wt;  // row = 64 float4s
    float4v acc0 = {0.f, 0.f, 0.f, 0.f};
    float4v acc1 = {0.f, 0.f, 0.f, 0.f};
#pragma unroll 4
    for (int e = 0; e < 256; ++e) {
        float xv = xs[rw][e];                       // wave-uniform broadcast
        float4v w1 = wt[(size_t)e * 64 + fq];       // Wt[e][f0..f0+3]   (pi)
        float4v w2 = wt[(size_t)(e + 256) * 64 + fq]; // Wt[256+e][...]  (pj)
        acc0 += w1 * xv;
        acc1 += w2 * xv;
    }
    const float4v bv = *(const float4v*)(bias + fq * 4);
    *(float4v*)(pib + (size_t)(r0 + rw) * 256 + fq * 4) = acc0 + bv;
    *(float4v*)(pj  + (size_t)(r0 + rw) * 256 + fq * 4) = acc1;
}

// Kernel 2: out[bi, j, f] = pib[bi, f] + pj[b*256+j, f],  bi = b*256+i.
// v3: PLAIN stores instead of nontemporal. The rocclr fill sustains
// 6.4 TB/s with plain stores; round-1 showed bcast_add is geometry-
// invariant, so the untested variable is the NT store path itself.
// pj is 1 MB and re-read at us intervals -> L2 write-allocate pollution
// risk is bounded. Structure unchanged from round 1 (2048 blocks,
// 32-row streams, full occupancy in one dispatch round).
__global__ __launch_bounds__(256) void bcast_add(
    const float* __restrict__ pib, const float* __restrict__ pj,
    float* __restrict__ out) {
    const int bi   = blockIdx.x >> 1;    // b*256 + i
    const int half = blockIdx.x & 1;
    const int t = threadIdx.x;
    const int w = t >> 6;                // wave 0..3
    const int f0 = (t & 63) * 4;
    const int b = bi >> 8;
    const int j0 = half * 128 + w * 32;

    const float4v a = *(const float4v*)(pib + (size_t)bi * 256 + f0);
    const float* pjbase = pj + ((size_t)(b * 256 + j0)) * 256 + f0;
    float* obase = out + (((size_t)bi * 256) + j0) * 256 + f0;
#pragma unroll 8
    for (int jj = 0; jj < 32; ++jj) {
        float4v p = *(const float4v*)(pjbase + (size_t)jj * 256);
        *(float4v*)(obase + (size_t)jj * 256) = a + p;
    }
}

extern "C" void kernel_launch(void* const* d_in, const int* in_sizes, int n_in,
                              void* d_out, int out_size, void* d_ws, size_t ws_size,
                              hipStream_t stream) {
    const float* x    = (const float*)d_in[0];  // (4,256,256) fp32
    const float* W    = (const float*)d_in[1];  // (256,512)   fp32
    const float* bias = (const float*)d_in[2];  // (256,)      fp32
    float* out = (float*)d_out;                 // (4,256,256,256) fp32

    float* pib = (float*)d_ws;            // 1024*256 fp32 = 1 MiB
    float* pj  = pib + 1024 * 256;        // 1024*256 fp32 = 1 MiB
    float* Wt  = pj  + 1024 * 256;        // 512*256   fp32 = 512 KiB

    transposeW<<<32, 256, 0, stream>>>(W, Wt);
    gemm_pipj<<<256, 256, 0, stream>>>(x, Wt, bias, pib, pj);
    bcast_add<<<2048, 256, 0, stream>>>(pib, pj, out);
}

// Round 3
// 265.862 us; speedup vs baseline: 1.0700x; 1.0540x over previous
//
#include <hip/hip_runtime.h>

typedef __attribute__((ext_vector_type(4))) float float4v;

// Kernel 0: Wt[c][a] = W[a][c].  W is (256, 512) row-major; Wt is (512, 256).
// Classic LDS tile transpose: both global read and write fully coalesced.
// 512 KB once -> ~2 us.
__global__ __launch_bounds__(256) void transposeW(
    const float* __restrict__ W, float* __restrict__ Wt) {
    __shared__ float tile[64][65];
    const int ta = blockIdx.x & 3;   // row-tile of W (f), 0..3
    const int tc = blockIdx.x >> 2;  // col-tile of W (c), 0..7
    const int lx = threadIdx.x & 63;
    const int ly = threadIdx.x >> 6; // 0..3
#pragma unroll
    for (int rr = 0; rr < 64; rr += 4)
        tile[rr + ly][lx] = W[(size_t)(ta * 64 + rr + ly) * 512 + tc * 64 + lx];
    __syncthreads();
#pragma unroll
    for (int rr = 0; rr < 64; rr += 4)
        Wt[(size_t)(tc * 64 + rr + ly) * 256 + ta * 64 + lx] = tile[lx][rr + ly];
}

// Kernel 1: pib[row,f] = sum_e x[row,e]*Wt[e,f] + bias[f]
//           pj [row,f] = sum_e x[row,e]*Wt[256+e,f]
// v3: e-SPLIT across waves. Round-2 version had all 4 waves reading the
// SAME Wt stream (2 MB/block from L2, 512 MB chip-wide, 512 loads/thread
// latency-exposed at 1 wave/SIMD). Now wave rw covers e-quarter
// rw*64..rw*64+63 for ALL 4 rows -> W read once per block (512 KB,
// 128 MB chip-wide ~ 3.7 us L2 floor), 128 loads/thread, then a 32 KB
// LDS cross-wave reduction. FLOPs unchanged (2048 FMA/thread).
__global__ __launch_bounds__(256) void gemm_pipj(
    const float* __restrict__ x, const float* __restrict__ Wt,
    const float* __restrict__ bias,
    float* __restrict__ pib, float* __restrict__ pj) {
    const int r0 = blockIdx.x * 4;
    const int t = threadIdx.x;
    const int rw = t >> 6;           // wave id = e-quarter (and later: row)
    const int fq = t & 63;           // float4 index within f
    __shared__ float xs[4][256];
    __shared__ float4v red[4][4][2][64];   // [wave][row][half][fq] = 32 KB
#pragma unroll
    for (int k = 0; k < 4; ++k)
        ((float*)xs)[k * 256 + t] = x[(size_t)r0 * 256 + k * 256 + t];
    __syncthreads();

    const float4v* wt = (const float4v*)Wt;  // row = 64 float4s
    float4v acc0[4] = {{0,0,0,0},{0,0,0,0},{0,0,0,0},{0,0,0,0}};
    float4v acc1[4] = {{0,0,0,0},{0,0,0,0},{0,0,0,0},{0,0,0,0}};
#pragma unroll 4
    for (int ee = 0; ee < 64; ++ee) {
        const int e = rw * 64 + ee;
        float4v w1 = wt[(size_t)e * 64 + fq];         // Wt[e][f0..f0+3]
        float4v w2 = wt[(size_t)(e + 256) * 64 + fq]; // Wt[256+e][...]
#pragma unroll
        for (int r = 0; r < 4; ++r) {
            float xv = xs[r][e];                      // wave-uniform broadcast
            acc0[r] += w1 * xv;
            acc1[r] += w2 * xv;
        }
    }
#pragma unroll
    for (int r = 0; r < 4; ++r) {
        red[rw][r][0][fq] = acc0[r];
        red[rw][r][1][fq] = acc1[r];
    }
    __syncthreads();
    // wave rw finalizes row rw: sum the 4 e-quarter partials
    float4v s0 = red[0][rw][0][fq] + red[1][rw][0][fq]
               + red[2][rw][0][fq] + red[3][rw][0][fq];
    float4v s1 = red[0][rw][1][fq] + red[1][rw][1][fq]
               + red[2][rw][1][fq] + red[3][rw][1][fq];
    const float4v bv = *(const float4v*)(bias + fq * 4);
    *(float4v*)(pib + (size_t)(r0 + rw) * 256 + fq * 4) = s0 + bv;
    *(float4v*)(pj  + (size_t)(r0 + rw) * 256 + fq * 4) = s1;
}

// Kernel 2: out[bi, j, f] = pib[bi, f] + pj[b*256+j, f],  bi = b*256+i.
// Geometry- and store-type-invariant across rounds 1-2 -> treated as at
// its write floor (268 MB @ ~6.5 TB/s ~ 41 us). 2048 blocks x 4 waves =
// 32 waves/CU, 32-row streams, plain float4 stores.
__global__ __launch_bounds__(256) void bcast_add(
    const float* __restrict__ pib, const float* __restrict__ pj,
    float* __restrict__ out) {
    const int bi   = blockIdx.x >> 1;    // b*256 + i
    const int half = blockIdx.x & 1;
    const int t = threadIdx.x;
    const int w = t >> 6;                // wave 0..3
    const int f0 = (t & 63) * 4;
    const int b = bi >> 8;
    const int j0 = half * 128 + w * 32;

    const float4v a = *(const float4v*)(pib + (size_t)bi * 256 + f0);
    const float* pjbase = pj + ((size_t)(b * 256 + j0)) * 256 + f0;
    float* obase = out + (((size_t)bi * 256) + j0) * 256 + f0;
#pragma unroll 8
    for (int jj = 0; jj < 32; ++jj) {
        float4v p = *(const float4v*)(pjbase + (size_t)jj * 256);
        *(float4v*)(obase + (size_t)jj * 256) = a + p;
    }
}

extern "C" void kernel_launch(void* const* d_in, const int* in_sizes, int n_in,
                              void* d_out, int out_size, void* d_ws, size_t ws_size,
                              hipStream_t stream) {
    const float* x    = (const float*)d_in[0];  // (4,256,256) fp32
    const float* W    = (const float*)d_in[1];  // (256,512)   fp32
    const float* bias = (const float*)d_in[2];  // (256,)      fp32
    float* out = (float*)d_out;                 // (4,256,256,256) fp32

    float* pib = (float*)d_ws;            // 1024*256 fp32 = 1 MiB
    float* pj  = pib + 1024 * 256;        // 1024*256 fp32 = 1 MiB
    float* Wt  = pj  + 1024 * 256;        // 512*256   fp32 = 512 KiB

    transposeW<<<32, 256, 0, stream>>>(W, Wt);
    gemm_pipj<<<256, 256, 0, stream>>>(x, Wt, bias, pib, pj);
    bcast_add<<<2048, 256, 0, stream>>>(pib, pj, out);
}